// Round 1
// 27855.060 us; speedup vs baseline: 1.1612x; 1.1612x over previous
//
#include <hip/hip_runtime.h>
#include <math.h>

#define GROUPS   8
#define HIDDEN   2048
#define TSTEPS   4096
#define RADIUS_F 100.0f
#define BPG      32                 // blocks per group
#define NBLOCKS  (GROUPS * BPG)     // 256 = #CUs
#define BLOCK    512                // 8 waves
#define ROWS_PB  64                 // rows per block
#define GH       (GROUPS * HIDDEN)

// Weight tiers, per thread (each thread owns 64 float4 = 256 floats of one row,
// interleaved mod-8: f4 index = 8*j + c). 44+6+14 = 64.
#define J_REG  44    // float4 pinned in VGPRs (176 regs, persistent)
#define J_LDS  6     // float4 in LDS (6*512*16 = 48 KB/block)
#define J_TAIL 14    // float4 re-read per step; 3.67 MB/XCD -> L2-resident

typedef float vfloat4 __attribute__((ext_vector_type(4)));

// Persistent cooperative kernel, one device barrier per step.
// R4 change vs R3: weights no longer streamed from Infinity Cache each step
// (134 MB/step @ ~17 TB/s was the wall). Each CU's 512 KB slab now lives in
// 176 VGPRs/thread + 48 KB LDS + a 114 KB/block L2-resident tail.
// Interleaved mod-8 column ownership: h reads are 8-way broadcast
// conflict-free ds_read_b128 with pure immediate offsets; tail global reads
// are full-128B-line coalesced. Row reduce = 3 shfl_xor over phase lanes.
__global__ __launch_bounds__(BLOCK, 2) void esn_persistent(
    const float* __restrict__ x,      // [T]
    const float* __restrict__ W_ih,   // [H]
    const float* __restrict__ W_hh,   // [G,H,H]
    float* __restrict__ out,          // [T, G*H]
    float* preBuf,                    // 2 * G*H floats (double buffer)
    unsigned* ctr)                    // counters, 64-uint stride per group
{
    const int tid  = threadIdx.x;
    const int wave = tid >> 6;
    const int lane = tid & 63;
    const int g    = blockIdx.x & (GROUPS - 1);   // XCD affinity
    const int sub  = blockIdx.x >> 3;             // 0..31 within group
    const int rowBase = sub * ROWS_PB;
    const int r = tid >> 3;                       // local row 0..63
    const int c = tid & 7;                        // f4 phase 0..7

    __shared__ float  h_lds[HIDDEN];              // 8 KB
    __shared__ float4 wlds[J_LDS * BLOCK];        // 48 KB
    __shared__ float  wih_lds[ROWS_PB];
    __shared__ float  red[BLOCK / 64];

    const float4* row4 =
        (const float4*)(W_hh + ((size_t)(g * HIDDEN + rowBase + r)) * HIDDEN);

    // ---- one-time load: VGPR tier (persistent across all 4096 steps) ----
    float4 wreg[J_REG];
    #pragma unroll
    for (int j = 0; j < J_REG; ++j)
        wreg[j] = row4[8 * j + c];
    // ---- one-time load: LDS tier ----
    #pragma unroll
    for (int j = 0; j < J_LDS; ++j)
        wlds[j * BLOCK + tid] = row4[8 * (J_REG + j) + c];

    ((float4*)h_lds)[tid] = make_float4(0.f, 0.f, 0.f, 0.f);
    if (tid < ROWS_PB / 4)
        ((float4*)wih_lds)[tid] = ((const float4*)(W_ih + rowBase))[tid];
    __syncthreads();

    const float lr  = (float)(GROUPS - g) / (float)GROUPS;
    const float olr = 1.0f - lr;
    const float lrR = lr * RADIUS_F;

    const float4* tail4 = row4 + 8 * (J_REG + J_LDS) + c;  // tail4[8*j]
    const float4* h4c   = (const float4*)h_lds + c;        // h4c[8*j]
    const float4* wl4   = wlds + tid;                      // wl4[j*BLOCK]

    unsigned* myctr = ctr + g * 64;               // 256B apart per group

    for (int t = 0; t < TSTEPS; ++t) {
        const int buf = t & 1;
        float* pb = preBuf + (size_t)buf * GH + g * HIDDEN;
        const float xt = x[t];

        // ---- phase 1: one row-chunk dot per thread ----
        float acc = 0.f;

        // issue tail batch A early: 7 dwordx4 from L2 hide under VALU tier
        float4 ta[7], tb[7];
        #pragma unroll
        for (int j = 0; j < 7; ++j) ta[j] = tail4[8 * j];

        // VGPR tier: 44 f4, h via ds_read_b128 at immediate offsets
        #pragma unroll
        for (int j = 0; j < J_REG; ++j) {
            const float4 hv = h4c[8 * j];
            acc = fmaf(wreg[j].x, hv.x, acc);
            acc = fmaf(wreg[j].y, hv.y, acc);
            acc = fmaf(wreg[j].z, hv.z, acc);
            acc = fmaf(wreg[j].w, hv.w, acc);
        }
        // LDS tier: 6 f4
        #pragma unroll
        for (int j = 0; j < J_LDS; ++j) {
            const float4 wv = wl4[j * BLOCK];
            const float4 hv = h4c[8 * (J_REG + j)];
            acc = fmaf(wv.x, hv.x, acc);
            acc = fmaf(wv.y, hv.y, acc);
            acc = fmaf(wv.z, hv.z, acc);
            acc = fmaf(wv.w, hv.w, acc);
        }
        // fence: keep tail batch B's 28 in-flight regs out of the tier above
        __builtin_amdgcn_sched_barrier(0);
        #pragma unroll
        for (int j = 0; j < 7; ++j) tb[j] = tail4[8 * (7 + j)];
        #pragma unroll
        for (int j = 0; j < 7; ++j) {
            const float4 hv = h4c[8 * (J_REG + J_LDS + j)];
            acc = fmaf(ta[j].x, hv.x, acc);
            acc = fmaf(ta[j].y, hv.y, acc);
            acc = fmaf(ta[j].z, hv.z, acc);
            acc = fmaf(ta[j].w, hv.w, acc);
        }
        #pragma unroll
        for (int j = 0; j < 7; ++j) {
            const float4 hv = h4c[8 * (J_REG + J_LDS + 7 + j)];
            acc = fmaf(tb[j].x, hv.x, acc);
            acc = fmaf(tb[j].y, hv.y, acc);
            acc = fmaf(tb[j].z, hv.z, acc);
            acc = fmaf(tb[j].w, hv.w, acc);
        }

        // row total = sum over the row's 8 phase lanes (lane bits 0..2)
        acc += __shfl_xor(acc, 1, 64);
        acc += __shfl_xor(acc, 2, 64);
        acc += __shfl_xor(acc, 4, 64);
        if (c == 0) {
            const float pre = fmaf(xt, wih_lds[r], acc);
            __hip_atomic_store(&pb[rowBase + r], pre,
                               __ATOMIC_RELAXED, __HIP_MEMORY_SCOPE_AGENT);
        }

        // ---- per-group device barrier (counter on private line) ----
        __syncthreads();   // drains vmcnt -> pre stores visible at coherence point
        if (tid == 0) {
            __hip_atomic_fetch_add(myctr, 1u, __ATOMIC_RELEASE, __HIP_MEMORY_SCOPE_AGENT);
            const unsigned tgt = (unsigned)(BPG * (t + 1));   // monotonic
            while (__hip_atomic_load(myctr, __ATOMIC_RELAXED, __HIP_MEMORY_SCOPE_AGENT) < tgt)
                __builtin_amdgcn_s_sleep(2);
        }
        __syncthreads();

        // ---- phase 3: read full pre (agent-scope), norm, h update ----
        float* pg = preBuf + (size_t)buf * GH + g * HIDDEN;
        const float p0 = __hip_atomic_load(&pg[tid * 4 + 0], __ATOMIC_RELAXED, __HIP_MEMORY_SCOPE_AGENT);
        const float p1 = __hip_atomic_load(&pg[tid * 4 + 1], __ATOMIC_RELAXED, __HIP_MEMORY_SCOPE_AGENT);
        const float p2 = __hip_atomic_load(&pg[tid * 4 + 2], __ATOMIC_RELAXED, __HIP_MEMORY_SCOPE_AGENT);
        const float p3 = __hip_atomic_load(&pg[tid * 4 + 3], __ATOMIC_RELAXED, __HIP_MEMORY_SCOPE_AGENT);

        float ss = p0 * p0 + p1 * p1 + p2 * p2 + p3 * p3;
        #pragma unroll
        for (int off = 32; off; off >>= 1)
            ss += __shfl_xor(ss, off, 64);
        if (lane == 0) red[wave] = ss;
        __syncthreads();
        float s = 0.f;
        #pragma unroll
        for (int w = 0; w < BLOCK / 64; ++w) s += red[w];
        const float sc = lrR / sqrtf(s);          // identical in every block

        const float4 h4 = *(const float4*)&h_lds[tid * 4];
        float4 hn;
        hn.x = olr * h4.x + sc * p0;
        hn.y = olr * h4.y + sc * p1;
        hn.z = olr * h4.z + sc * p2;
        hn.w = olr * h4.w + sc * p3;
        *(float4*)&h_lds[tid * 4] = hn;

        // our own 64 cols -> out, straight from registers, nontemporal
        if (tid >= rowBase / 4 && tid < rowBase / 4 + ROWS_PB / 4) {
            vfloat4 hv4;
            hv4.x = hn.x; hv4.y = hn.y; hv4.z = hn.z; hv4.w = hn.w;
            vfloat4* op = (vfloat4*)&out[(size_t)t * GH + g * HIDDEN + tid * 4];
            __builtin_nontemporal_store(hv4, op);
        }
        __syncthreads();   // h_lds ready for next step
    }
}

extern "C" void kernel_launch(void* const* d_in, const int* in_sizes, int n_in,
                              void* d_out, int out_size, void* d_ws, size_t ws_size,
                              hipStream_t stream) {
    const float* x   = (const float*)d_in[0];   // [4096]
    const float* Wih = (const float*)d_in[1];   // [2048]
    const float* Whh = (const float*)d_in[2];   // [8*2048*2048]
    float* out = (float*)d_out;

    unsigned* ctr  = (unsigned*)d_ws;                       // 8 counters, 256B stride
    float* preBuf  = (float*)((char*)d_ws + 4096);          // 2 * 64KB

    (void)hipMemsetAsync(d_ws, 0, 4096, stream);            // zero counters (ws re-poisoned)

    void* args[] = { (void*)&x, (void*)&Wih, (void*)&Whh,
                     (void*)&out, (void*)&preBuf, (void*)&ctr };
    (void)hipLaunchCooperativeKernel((const void*)esn_persistent,
                                     dim3(NBLOCKS), dim3(BLOCK), args, 0, stream);
}